// Round 1
// baseline (2632.407 us; speedup 1.0000x reference)
//
#include <hip/hip_runtime.h>

// Sinkhorn EMD (ApproximatedEMDLoss), B=16, N=2048, D=3, eps=0.01, 50 iters.
//
// Reduction used: with s_j = sum_i K_ij (column sums),
//   u = r / (K_tilde v)  = r / (K w),  w = v / s
//   v = c / (K_tilde^T u) = c * s / (K^T u)
// so only plain matvecs against K are needed. K is recomputed on the fly
// (compute-bound) instead of materialized (memory-bound: 100x256MiB).

namespace {

constexpr int kB = 16;
constexpr int kN = 2048;
constexpr float kR = 1.0f / (float)kN;            // r = c = 1/n
// exp(-d/0.01) = exp2(d * -100*log2(e))
constexpr float kNegScale = -144.26950408889634f;

constexpr int ROWS_PER_BLOCK = 32;
constexpr int SPLITS = 8;                          // j-splits per row
constexpr int CHUNK = kN / SPLITS;                 // 256
constexpr int BLOCKS_PER_BATCH = kN / ROWS_PER_BLOCK; // 64
constexpr int GRID = kB * BLOCKS_PER_BATCH;        // 1024 blocks = 4/CU

// skew so the 8 per-wave broadcast addresses hit disjoint bank quads
__device__ __forceinline__ int skew(int j) { return j + (j >> 8); }

// MODE 0: w_j = 1 (column-sum pass).  MODE 1: w_j = mult / raw[j].
template <int MODE>
__global__ __launch_bounds__(256, 4) void emd_matvec(
    const float* __restrict__ rowpts,   // [B,N,3] points indexing the output
    const float* __restrict__ colpts,   // [B,N,3] points being summed over
    const float* __restrict__ raw,      // [B,N] raw sums from previous pass
    float mult, float* __restrict__ out /* [B,N] */) {
  __shared__ float4 cw[kN + SPLITS];
  const int b = blockIdx.x >> 6;                     // /BLOCKS_PER_BATCH
  const int rowbase = (blockIdx.x & 63) * ROWS_PER_BLOCK;
  const float* cp = colpts + b * kN * 3;

  for (int j = threadIdx.x; j < kN; j += 256) {
    float w;
    if (MODE == 0) w = 1.0f;
    else           w = mult / raw[b * kN + j];
    cw[skew(j)] = make_float4(cp[3 * j], cp[3 * j + 1], cp[3 * j + 2], w);
  }
  __syncthreads();

  const int split = threadIdx.x & (SPLITS - 1);      // low bits -> same wave
  const int row = rowbase + (threadIdx.x >> 3);
  const float* rp = rowpts + (b * kN + row) * 3;
  const float x0 = rp[0], x1 = rp[1], x2 = rp[2];

  float acc = 0.0f;
  const int base = split * (CHUNK + 1);              // skewed chunk base
#pragma unroll 8
  for (int k = 0; k < CHUNK; ++k) {
    float4 yw = cw[base + k];
    float dx = x0 - yw.x, dy = x1 - yw.y, dz = x2 - yw.z;
    float d2 = fmaxf(fmaf(dx, dx, fmaf(dy, dy, dz * dz)), 1e-12f);
    float d = __builtin_amdgcn_sqrtf(d2);
    acc = fmaf(__builtin_amdgcn_exp2f(d * kNegScale), yw.w, acc);
  }
  // reduce the 8 split-lanes (consecutive within the wave)
  acc += __shfl_xor(acc, 1);
  acc += __shfl_xor(acc, 2);
  acc += __shfl_xor(acc, 4);
  if (split == 0) out[b * kN + row] = acc;
}

// loss = mean_b sum_ij u_i K_ij v_j C_ij, u_i = r/p_i, v_j = c*s_j/q_j
__global__ __launch_bounds__(256, 4) void emd_loss(
    const float* __restrict__ rowpts, const float* __restrict__ colpts,
    const float* __restrict__ s, const float* __restrict__ q,
    const float* __restrict__ p, float* __restrict__ out) {
  __shared__ float4 cw[kN + SPLITS];
  __shared__ float wavered[4];
  const int b = blockIdx.x >> 6;
  const int rowbase = (blockIdx.x & 63) * ROWS_PER_BLOCK;
  const float* cp = colpts + b * kN * 3;

  for (int j = threadIdx.x; j < kN; j += 256) {
    float v = kR * s[b * kN + j] / q[b * kN + j];
    cw[skew(j)] = make_float4(cp[3 * j], cp[3 * j + 1], cp[3 * j + 2], v);
  }
  __syncthreads();

  const int split = threadIdx.x & (SPLITS - 1);
  const int row = rowbase + (threadIdx.x >> 3);
  const float* rp = rowpts + (b * kN + row) * 3;
  const float x0 = rp[0], x1 = rp[1], x2 = rp[2];
  const float u = kR / p[b * kN + row];

  float acc = 0.0f;
  const int base = split * (CHUNK + 1);
#pragma unroll 8
  for (int k = 0; k < CHUNK; ++k) {
    float4 yw = cw[base + k];
    float dx = x0 - yw.x, dy = x1 - yw.y, dz = x2 - yw.z;
    float d2 = fmaxf(fmaf(dx, dx, fmaf(dy, dy, dz * dz)), 1e-12f);
    float d = __builtin_amdgcn_sqrtf(d2);
    float e = __builtin_amdgcn_exp2f(d * kNegScale);
    acc = fmaf(e * d, yw.w, acc);                    // K_ij * C_ij * v_j
  }
  acc *= u;

#pragma unroll
  for (int m = 1; m < 64; m <<= 1) acc += __shfl_xor(acc, m);
  const int lane = threadIdx.x & 63;
  const int wave = threadIdx.x >> 6;
  if (lane == 0) wavered[wave] = acc;
  __syncthreads();
  if (threadIdx.x == 0) {
    float t = (wavered[0] + wavered[1] + wavered[2] + wavered[3]) * (1.0f / kB);
    atomicAdd(out, t);
  }
}

}  // namespace

extern "C" void kernel_launch(void* const* d_in, const int* in_sizes, int n_in,
                              void* d_out, int out_size, void* d_ws, size_t ws_size,
                              hipStream_t stream) {
  const float* pc1 = (const float*)d_in[0];  // x (rows i)
  const float* pc2 = (const float*)d_in[1];  // y (cols j); pc3 unused
  float* s = (float*)d_ws;                   // [B,N] column sums of K
  float* p = s + kB * kN;                    // [B,N] raw K w   (u = r/p)
  float* q = p + kB * kN;                    // [B,N] raw K^T u (v = c s/q)

  dim3 grid(GRID), block(256);

  // s_j = sum_i K_ij : output indexed by j -> rows=pc2, cols=pc1
  hipLaunchKernelGGL((emd_matvec<0>), grid, block, 0, stream,
                     pc2, pc1, (const float*)nullptr, 0.0f, s);
  // iter 0: v0 = 1 -> w0 = 1/s
  hipLaunchKernelGGL((emd_matvec<1>), grid, block, 0, stream,
                     pc1, pc2, s, 1.0f, p);
  hipLaunchKernelGGL((emd_matvec<1>), grid, block, 0, stream,
                     pc2, pc1, p, kR, q);
  for (int it = 1; it < 50; ++it) {
    hipLaunchKernelGGL((emd_matvec<1>), grid, block, 0, stream,
                       pc1, pc2, q, kR, p);
    hipLaunchKernelGGL((emd_matvec<1>), grid, block, 0, stream,
                       pc2, pc1, p, kR, q);
  }
  hipMemsetAsync(d_out, 0, sizeof(float), stream);
  hipLaunchKernelGGL(emd_loss, grid, block, 0, stream,
                     pc1, pc2, s, q, p, (float*)d_out);
}

// Round 2
// 2468.207 us; speedup vs baseline: 1.0665x; 1.0665x over previous
//
#include <hip/hip_runtime.h>

// Sinkhorn EMD (ApproximatedEMDLoss), B=16, N=2048, D=3, eps=0.01, 50 iters.
//
// With s_j = sum_i K_ij (column sums):
//   u = r / (K w),  w = v / s
//   v = c * s / (K^T u)
// Only plain matvecs against K are needed; K is recomputed on the fly.
//
// R2 changes vs R1: coordinates pre-scaled by 100*log2(e) so the per-pair
// multiply disappears and exp2 takes sqrt's result via a free neg modifier;
// fmax clamp dropped (direct-form d2 >= 0); 4 rows register-blocked per
// thread to amortize the ds_read_b128 4x. Model: 33 cyc/wave-pair -> ~14us/pass.

namespace {

constexpr int kB = 16;
constexpr int kN = 2048;
constexpr float kR = 1.0f / (float)kN;             // r = c = 1/n
constexpr float kScale = 144.26950408889634f;      // 100 * log2(e)

constexpr int SPLITS = 16;                          // j-splits per row
constexpr int RPT = 4;                              // rows per thread
constexpr int CHUNK = kN / SPLITS;                  // 128
constexpr int ROWS_PER_BLOCK = (256 / SPLITS) * RPT;      // 64
constexpr int BLOCKS_PER_BATCH = kN / ROWS_PER_BLOCK;     // 32
constexpr int GRID = kB * BLOCKS_PER_BATCH;               // 512 = 2/CU

// skew: chunk s starts at 129*s -> the 16 per-wave broadcast addresses are
// only 2-way aliased per float4-bank-group (free).
__device__ __forceinline__ int skew(int j) { return j + (j >> 7); }

// MODE 0: w_j = 1 (column-sum pass).  MODE 1: w_j = mult / raw[j].
template <int MODE>
__global__ __launch_bounds__(256, 4) void emd_matvec(
    const float* __restrict__ rowpts,   // [B,N,3] points indexing the output
    const float* __restrict__ colpts,   // [B,N,3] points being summed over
    const float* __restrict__ raw,      // [B,N] raw sums from previous pass
    float mult, float* __restrict__ out /* [B,N] */) {
  __shared__ float4 cw[kN + SPLITS];
  const int b = blockIdx.x >> 5;                     // / BLOCKS_PER_BATCH
  const int rowbase = (blockIdx.x & 31) * ROWS_PER_BLOCK;
  const float* cp = colpts + b * kN * 3;

  for (int j = threadIdx.x; j < kN; j += 256) {
    float w;
    if (MODE == 0) w = 1.0f;
    else           w = mult / raw[b * kN + j];
    cw[skew(j)] = make_float4(cp[3 * j] * kScale, cp[3 * j + 1] * kScale,
                              cp[3 * j + 2] * kScale, w);
  }
  __syncthreads();

  const int split = threadIdx.x & (SPLITS - 1);      // lane bits 0..3
  const int row0 = rowbase + (threadIdx.x >> 4) * RPT;
  const float* rp = rowpts + (b * kN + row0) * 3;
  float x[RPT][3];
#pragma unroll
  for (int rr = 0; rr < RPT; ++rr) {
    x[rr][0] = rp[3 * rr + 0] * kScale;
    x[rr][1] = rp[3 * rr + 1] * kScale;
    x[rr][2] = rp[3 * rr + 2] * kScale;
  }

  float acc[RPT] = {0.f, 0.f, 0.f, 0.f};
  const int base = split * (CHUNK + 1);              // skewed chunk base
#pragma unroll 4
  for (int k = 0; k < CHUNK; ++k) {
    float4 yw = cw[base + k];
#pragma unroll
    for (int rr = 0; rr < RPT; ++rr) {
      float dx = x[rr][0] - yw.x, dy = x[rr][1] - yw.y, dz = x[rr][2] - yw.z;
      float d2 = fmaf(dx, dx, fmaf(dy, dy, dz * dz));
      float e = __builtin_amdgcn_exp2f(-__builtin_amdgcn_sqrtf(d2));
      acc[rr] = fmaf(e, yw.w, acc[rr]);
    }
  }
  // reduce the 16 split-lanes (lane bits 0..3)
#pragma unroll
  for (int m = 1; m < SPLITS; m <<= 1) {
#pragma unroll
    for (int rr = 0; rr < RPT; ++rr) acc[rr] += __shfl_xor(acc[rr], m);
  }
  if (split == 0) {
    *reinterpret_cast<float4*>(out + b * kN + row0) =
        make_float4(acc[0], acc[1], acc[2], acc[3]);
  }
}

// loss = mean_b sum_ij u_i K_ij v_j C_ij, u_i = r/p_i, v_j = c*s_j/q_j
// In scaled units: K_ij*C_ij = e * ds / kScale with ds = sqrt(d2_scaled).
__global__ __launch_bounds__(256, 4) void emd_loss(
    const float* __restrict__ rowpts, const float* __restrict__ colpts,
    const float* __restrict__ s, const float* __restrict__ q,
    const float* __restrict__ p, float* __restrict__ out) {
  __shared__ float4 cw[kN + SPLITS];
  __shared__ float wavered[4];
  const int b = blockIdx.x >> 5;
  const int rowbase = (blockIdx.x & 31) * ROWS_PER_BLOCK;
  const float* cp = colpts + b * kN * 3;

  for (int j = threadIdx.x; j < kN; j += 256) {
    float v = kR * s[b * kN + j] / q[b * kN + j];
    cw[skew(j)] = make_float4(cp[3 * j] * kScale, cp[3 * j + 1] * kScale,
                              cp[3 * j + 2] * kScale, v);
  }
  __syncthreads();

  const int split = threadIdx.x & (SPLITS - 1);
  const int row0 = rowbase + (threadIdx.x >> 4) * RPT;
  const float* rp = rowpts + (b * kN + row0) * 3;
  float x[RPT][3], u[RPT];
#pragma unroll
  for (int rr = 0; rr < RPT; ++rr) {
    x[rr][0] = rp[3 * rr + 0] * kScale;
    x[rr][1] = rp[3 * rr + 1] * kScale;
    x[rr][2] = rp[3 * rr + 2] * kScale;
    u[rr] = kR / p[b * kN + row0 + rr];
  }

  float acc[RPT] = {0.f, 0.f, 0.f, 0.f};
  const int base = split * (CHUNK + 1);
#pragma unroll 4
  for (int k = 0; k < CHUNK; ++k) {
    float4 yw = cw[base + k];
#pragma unroll
    for (int rr = 0; rr < RPT; ++rr) {
      float dx = x[rr][0] - yw.x, dy = x[rr][1] - yw.y, dz = x[rr][2] - yw.z;
      float d2 = fmaf(dx, dx, fmaf(dy, dy, dz * dz));
      float ds = __builtin_amdgcn_sqrtf(d2);
      float e = __builtin_amdgcn_exp2f(-ds);
      acc[rr] = fmaf(e * ds, yw.w, acc[rr]);         // (K*C*kScale) * v
    }
  }
#pragma unroll
  for (int m = 1; m < SPLITS; m <<= 1) {
#pragma unroll
    for (int rr = 0; rr < RPT; ++rr) acc[rr] += __shfl_xor(acc[rr], m);
  }
  // per-thread row total (valid on split==0 lanes; zero elsewhere)
  float t = 0.f;
  if (split == 0) {
#pragma unroll
    for (int rr = 0; rr < RPT; ++rr) t = fmaf(u[rr], acc[rr], t);
  }
  // reduce over the 4 row-groups in this wave (lane bits 4..5)
  t += __shfl_xor(t, 16);
  t += __shfl_xor(t, 32);
  const int lane = threadIdx.x & 63;
  const int wave = threadIdx.x >> 6;
  if (lane == 0) wavered[wave] = t;
  __syncthreads();
  if (threadIdx.x == 0) {
    float blocksum = wavered[0] + wavered[1] + wavered[2] + wavered[3];
    atomicAdd(out, blocksum * (1.0f / (kScale * (float)kB)));
  }
}

}  // namespace

extern "C" void kernel_launch(void* const* d_in, const int* in_sizes, int n_in,
                              void* d_out, int out_size, void* d_ws, size_t ws_size,
                              hipStream_t stream) {
  const float* pc1 = (const float*)d_in[0];  // x (rows i)
  const float* pc2 = (const float*)d_in[1];  // y (cols j); pc3 unused
  float* s = (float*)d_ws;                   // [B,N] column sums of K
  float* p = s + kB * kN;                    // [B,N] raw K w   (u = r/p)
  float* q = p + kB * kN;                    // [B,N] raw K^T u (v = c s/q)

  dim3 grid(GRID), block(256);

  // s_j = sum_i K_ij : output indexed by j -> rows=pc2, cols=pc1
  hipLaunchKernelGGL((emd_matvec<0>), grid, block, 0, stream,
                     pc2, pc1, (const float*)nullptr, 0.0f, s);
  // iter 0: v0 = 1 -> w0 = 1/s
  hipLaunchKernelGGL((emd_matvec<1>), grid, block, 0, stream,
                     pc1, pc2, s, 1.0f, p);
  hipLaunchKernelGGL((emd_matvec<1>), grid, block, 0, stream,
                     pc2, pc1, p, kR, q);
  for (int it = 1; it < 50; ++it) {
    hipLaunchKernelGGL((emd_matvec<1>), grid, block, 0, stream,
                       pc1, pc2, q, kR, p);
    hipLaunchKernelGGL((emd_matvec<1>), grid, block, 0, stream,
                       pc2, pc1, p, kR, q);
  }
  hipMemsetAsync(d_out, 0, sizeof(float), stream);
  hipLaunchKernelGGL(emd_loss, grid, block, 0, stream,
                     pc1, pc2, s, q, p, (float*)d_out);
}

// Round 4
// 2443.089 us; speedup vs baseline: 1.0775x; 1.0103x over previous
//
#include <hip/hip_runtime.h>

// Sinkhorn EMD (ApproximatedEMDLoss), B=16, N=2048, D=3, eps=0.01, 50 iters.
//
// With s_j = sum_i K_ij (column sums):
//   u = r / (K w),  w = v / s
//   v = c * s / (K^T u)
// Only plain matvecs against K are needed; K is recomputed on the fly.
//
// R3 change vs R2: occupancy. R2 ran 2 waves/SIMD (512 blocks = 2/CU) and
// measured ~225 cyc/k-iter vs ~132 modeled issue cycles -> latency-bound.
// Now SPLITS=16, RPT=2, 32 rows/block, grid 1024 = 4 blocks/CU = 4 waves/SIMD,
// LDS 33KB x 4 = 132KB/CU (fits 160KB). Unroll 8 to cluster ds_reads.

namespace {

constexpr int kB = 16;
constexpr int kN = 2048;
constexpr float kR = 1.0f / (float)kN;             // r = c = 1/n
constexpr float kScale = 144.26950408889634f;      // 100 * log2(e)

constexpr int SPLITS = 16;                          // j-splits per row
constexpr int RPT = 2;                              // rows per thread
constexpr int CHUNK = kN / SPLITS;                  // 128
constexpr int ROWS_PER_BLOCK = (256 / SPLITS) * RPT;      // 32
constexpr int BLOCKS_PER_BATCH = kN / ROWS_PER_BLOCK;     // 64
constexpr int GRID = kB * BLOCKS_PER_BATCH;               // 1024 = 4/CU

// skew: chunk s base = s*(CHUNK+1) float4s -> start bank 4*(s mod 8):
// the 16 per-wave broadcast addresses are only 2-way bank-aliased (free).
__device__ __forceinline__ int skew(int j) { return j + (j >> 7); }

// MODE 0: w_j = 1 (column-sum pass).  MODE 1: w_j = mult / raw[j].
template <int MODE>
__global__ __launch_bounds__(256, 4) void emd_matvec(
    const float* __restrict__ rowpts,   // [B,N,3] points indexing the output
    const float* __restrict__ colpts,   // [B,N,3] points being summed over
    const float* __restrict__ raw,      // [B,N] raw sums from previous pass
    float mult, float* __restrict__ out /* [B,N] */) {
  __shared__ float4 cw[kN + SPLITS];
  const int b = blockIdx.x >> 6;                     // / BLOCKS_PER_BATCH
  const int rowbase = (blockIdx.x & 63) * ROWS_PER_BLOCK;
  const float* cp = colpts + b * kN * 3;

  for (int j = threadIdx.x; j < kN; j += 256) {
    float w;
    if (MODE == 0) w = 1.0f;
    else           w = mult / raw[b * kN + j];
    cw[skew(j)] = make_float4(cp[3 * j] * kScale, cp[3 * j + 1] * kScale,
                              cp[3 * j + 2] * kScale, w);
  }
  __syncthreads();

  const int split = threadIdx.x & (SPLITS - 1);      // lane bits 0..3
  const int row0 = rowbase + (threadIdx.x >> 4) * RPT;
  const float* rp = rowpts + (b * kN + row0) * 3;
  float x00 = rp[0] * kScale, x01 = rp[1] * kScale, x02 = rp[2] * kScale;
  float x10 = rp[3] * kScale, x11 = rp[4] * kScale, x12 = rp[5] * kScale;

  float acc0 = 0.f, acc1 = 0.f;
  const int base = split * (CHUNK + 1);              // skewed chunk base
#pragma unroll 8
  for (int k = 0; k < CHUNK; ++k) {
    float4 yw = cw[base + k];
    float dx0 = x00 - yw.x, dy0 = x01 - yw.y, dz0 = x02 - yw.z;
    float d20 = fmaf(dx0, dx0, fmaf(dy0, dy0, dz0 * dz0));
    float e0 = __builtin_amdgcn_exp2f(-__builtin_amdgcn_sqrtf(d20));
    acc0 = fmaf(e0, yw.w, acc0);
    float dx1 = x10 - yw.x, dy1 = x11 - yw.y, dz1 = x12 - yw.z;
    float d21 = fmaf(dx1, dx1, fmaf(dy1, dy1, dz1 * dz1));
    float e1 = __builtin_amdgcn_exp2f(-__builtin_amdgcn_sqrtf(d21));
    acc1 = fmaf(e1, yw.w, acc1);
  }
  // reduce the 16 split-lanes (lane bits 0..3)
#pragma unroll
  for (int m = 1; m < SPLITS; m <<= 1) {
    acc0 += __shfl_xor(acc0, m);
    acc1 += __shfl_xor(acc1, m);
  }
  if (split == 0) {
    *reinterpret_cast<float2*>(out + b * kN + row0) = make_float2(acc0, acc1);
  }
}

// loss = mean_b sum_ij u_i K_ij v_j C_ij, u_i = r/p_i, v_j = c*s_j/q_j
// In scaled units: K_ij*C_ij = e * ds / kScale with ds = sqrt(d2_scaled).
__global__ __launch_bounds__(256, 4) void emd_loss(
    const float* __restrict__ rowpts, const float* __restrict__ colpts,
    const float* __restrict__ s, const float* __restrict__ q,
    const float* __restrict__ p, float* __restrict__ out) {
  __shared__ float4 cw[kN + SPLITS];
  __shared__ float wavered[4];
  const int b = blockIdx.x >> 6;
  const int rowbase = (blockIdx.x & 63) * ROWS_PER_BLOCK;
  const float* cp = colpts + b * kN * 3;

  for (int j = threadIdx.x; j < kN; j += 256) {
    float v = kR * s[b * kN + j] / q[b * kN + j];
    cw[skew(j)] = make_float4(cp[3 * j] * kScale, cp[3 * j + 1] * kScale,
                              cp[3 * j + 2] * kScale, v);
  }
  __syncthreads();

  const int split = threadIdx.x & (SPLITS - 1);
  const int row0 = rowbase + (threadIdx.x >> 4) * RPT;
  const float* rp = rowpts + (b * kN + row0) * 3;
  float x00 = rp[0] * kScale, x01 = rp[1] * kScale, x02 = rp[2] * kScale;
  float x10 = rp[3] * kScale, x11 = rp[4] * kScale, x12 = rp[5] * kScale;
  float u0 = kR / p[b * kN + row0];
  float u1 = kR / p[b * kN + row0 + 1];

  float acc0 = 0.f, acc1 = 0.f;
  const int base = split * (CHUNK + 1);
#pragma unroll 8
  for (int k = 0; k < CHUNK; ++k) {
    float4 yw = cw[base + k];
    float dx0 = x00 - yw.x, dy0 = x01 - yw.y, dz0 = x02 - yw.z;
    float d20 = fmaf(dx0, dx0, fmaf(dy0, dy0, dz0 * dz0));
    float ds0 = __builtin_amdgcn_sqrtf(d20);
    acc0 = fmaf(__builtin_amdgcn_exp2f(-ds0) * ds0, yw.w, acc0);
    float dx1 = x10 - yw.x, dy1 = x11 - yw.y, dz1 = x12 - yw.z;
    float d21 = fmaf(dx1, dx1, fmaf(dy1, dy1, dz1 * dz1));
    float ds1 = __builtin_amdgcn_sqrtf(d21);
    acc1 = fmaf(__builtin_amdgcn_exp2f(-ds1) * ds1, yw.w, acc1);
  }
#pragma unroll
  for (int m = 1; m < SPLITS; m <<= 1) {
    acc0 += __shfl_xor(acc0, m);
    acc1 += __shfl_xor(acc1, m);
  }
  // per-thread row total (valid on split==0 lanes; zero elsewhere)
  float t = 0.f;
  if (split == 0) t = fmaf(u0, acc0, u1 * acc1);
  // reduce over the 4 row-groups in this wave (lane bits 4..5)
  t += __shfl_xor(t, 16);
  t += __shfl_xor(t, 32);
  const int lane = threadIdx.x & 63;
  const int wave = threadIdx.x >> 6;
  if (lane == 0) wavered[wave] = t;
  __syncthreads();
  if (threadIdx.x == 0) {
    float blocksum = wavered[0] + wavered[1] + wavered[2] + wavered[3];
    atomicAdd(out, blocksum * (1.0f / (kScale * (float)kB)));
  }
}

}  // namespace

extern "C" void kernel_launch(void* const* d_in, const int* in_sizes, int n_in,
                              void* d_out, int out_size, void* d_ws, size_t ws_size,
                              hipStream_t stream) {
  const float* pc1 = (const float*)d_in[0];  // x (rows i)
  const float* pc2 = (const float*)d_in[1];  // y (cols j); pc3 unused
  float* s = (float*)d_ws;                   // [B,N] column sums of K
  float* p = s + kB * kN;                    // [B,N] raw K w   (u = r/p)
  float* q = p + kB * kN;                    // [B,N] raw K^T u (v = c s/q)

  dim3 grid(GRID), block(256);

  // s_j = sum_i K_ij : output indexed by j -> rows=pc2, cols=pc1
  hipLaunchKernelGGL((emd_matvec<0>), grid, block, 0, stream,
                     pc2, pc1, (const float*)nullptr, 0.0f, s);
  // iter 0: v0 = 1 -> w0 = 1/s
  hipLaunchKernelGGL((emd_matvec<1>), grid, block, 0, stream,
                     pc1, pc2, s, 1.0f, p);
  hipLaunchKernelGGL((emd_matvec<1>), grid, block, 0, stream,
                     pc2, pc1, p, kR, q);
  for (int it = 1; it < 50; ++it) {
    hipLaunchKernelGGL((emd_matvec<1>), grid, block, 0, stream,
                       pc1, pc2, q, kR, p);
    hipLaunchKernelGGL((emd_matvec<1>), grid, block, 0, stream,
                       pc2, pc1, p, kR, q);
  }
  hipMemsetAsync(d_out, 0, sizeof(float), stream);
  hipLaunchKernelGGL(emd_loss, grid, block, 0, stream,
                     pc1, pc2, s, q, p, (float*)d_out);
}